// Round 6
// baseline (1041.145 us; speedup 1.0000x reference)
//
#include <hip/hip_runtime.h>

// Problem constants
constexpr int N_TOK = 8192;      // B*S
constexpr int D_IN  = 2048;
constexpr int H_OUT = 4096;
constexpr int NEXP  = 8;
constexpr float ENT_W = 0.1f;
constexpr float MAX_USAGE = 0.3f;

// GEMM tiling
constexpr int TM = 128;               // token-tile
constexpr int TH = 128;               // H-tile
constexpr int BK = 64;                // K-step (128 bytes bf16 per row)
constexpr int NKT = D_IN / BK;        // 32 K-tiles
constexpr int TILES_H = H_OUT / TH;   // 32
constexpr int TM_MAX  = N_TOK / TM;   // 64 worst-case token tiles per expert
constexpr int REGION  = 8192;         // per-expert list capacity
constexpr int BUFSZ   = TM * BK;      // shorts per A LDS buffer (8192)

typedef __attribute__((ext_vector_type(8))) short bf16x8;
typedef __attribute__((ext_vector_type(4))) float f32x4;

__device__ __forceinline__ short f2bf(float f) {
    unsigned u = __float_as_uint(f);
    u += 0x7FFF + ((u >> 16) & 1);   // RNE
    return (short)(u >> 16);
}

__device__ __forceinline__ void gload16(const void* g, void* l) {
    __builtin_amdgcn_global_load_lds(
        (const __attribute__((address_space(1))) unsigned int*)g,
        (__attribute__((address_space(3))) unsigned int*)l, 16, 0, 0);
}

// Opaque B-fragment load: compiler can't model it -> no auto vmcnt drains;
// our manual counted vmcnt + sched_barrier(0) certifies data (HK pattern).
#define LOADB(dst, base, OFF) \
    asm volatile("global_load_dwordx4 %0, %1, off offset:" #OFF \
                 : "=v"(dst) : "v"(base) : "memory")

// ---------------------------------------------------------------------------
// cvt_wb: fp32 expert_w -> bf16 in FRAGMENT-MAJOR layout wb2:
//   [e][kt(32)][hgrp(256)][k2(2)][lane(64)][8 elems]
// where lane = kg*16+rr maps to (h = hgrp*16+rr, k = kt*64+k2*32+kg*8).
// A wave's B-fragment load becomes one fully-coalesced 1KB global load.
// Writes coalesced 1KB/wave; reads 128B-segmented (16 rows) — acceptable.
// ---------------------------------------------------------------------------
__global__ __launch_bounds__(256) void cvt_wb(
    const float* __restrict__ in, short* __restrict__ out)
{
    const size_t total = (size_t)NEXP * 32 * 256 * 2 * 64;   // 8.39M chunks
    size_t stride = (size_t)gridDim.x * 256;
    for (size_t d = (size_t)blockIdx.x * 256 + threadIdx.x; d < total; d += stride) {
        int lane = d & 63;
        int k2   = (d >> 6) & 1;
        int hgrp = (d >> 7) & 255;
        int kt   = (d >> 15) & 31;
        int e    = (int)(d >> 20);
        int kg = lane >> 4, rr = lane & 15;
        int h = hgrp * 16 + rr;
        int k = kt * 64 + k2 * 32 + kg * 8;
        const float4* s = (const float4*)(in + ((size_t)e * H_OUT + h) * D_IN + k);
        float4 a = s[0], b = s[1];
        bf16x8 v;
        v[0] = f2bf(a.x); v[1] = f2bf(a.y); v[2] = f2bf(a.z); v[3] = f2bf(a.w);
        v[4] = f2bf(b.x); v[5] = f2bf(b.y); v[6] = f2bf(b.z); v[7] = f2bf(b.w);
        *(bf16x8*)(out + d * 8) = v;
    }
}

// ---------------------------------------------------------------------------
// Kernel 1: gating. One wave per token; fuses x -> bf16 conversion.
// ---------------------------------------------------------------------------
__global__ __launch_bounds__(256) void gate_kernel(
    const float* __restrict__ x, const float* __restrict__ gate_w,
    const float* __restrict__ gate_b, int* __restrict__ topk_idx,
    float* __restrict__ topk_w, float* __restrict__ ent_partial,
    short* __restrict__ xb)
{
    __shared__ float ent_s[4];
    const int wv = threadIdx.x >> 6;
    const int lane = threadIdx.x & 63;
    const int t = blockIdx.x * 4 + wv;

    float acc[NEXP];
#pragma unroll
    for (int e = 0; e < NEXP; ++e) acc[e] = 0.f;

    const float4* xr = (const float4*)(x + (size_t)t * D_IN);
    short* xbr = xb + (size_t)t * D_IN;
#pragma unroll
    for (int i = 0; i < D_IN / 256; ++i) {           // 8 iters
        float4 xv = xr[lane + i * 64];
        short4 s4;
        s4.x = f2bf(xv.x); s4.y = f2bf(xv.y); s4.z = f2bf(xv.z); s4.w = f2bf(xv.w);
        *(short4*)(xbr + i * 256 + lane * 4) = s4;
#pragma unroll
        for (int e = 0; e < NEXP; ++e) {
            float4 gv = ((const float4*)(gate_w + e * D_IN))[lane + i * 64];
            acc[e] += xv.x * gv.x + xv.y * gv.y + xv.z * gv.z + xv.w * gv.w;
        }
    }
#pragma unroll
    for (int e = 0; e < NEXP; ++e)
#pragma unroll
        for (int m = 32; m >= 1; m >>= 1) acc[e] += __shfl_xor(acc[e], m, 64);

    if (lane == 0) {
        float lg[NEXP], p[NEXP];
        float mx = -1e30f;
#pragma unroll
        for (int e = 0; e < NEXP; ++e) { lg[e] = acc[e] + gate_b[e]; mx = fmaxf(mx, lg[e]); }
        float s = 0.f;
#pragma unroll
        for (int e = 0; e < NEXP; ++e) { p[e] = expf(lg[e] - mx); s += p[e]; }
        float inv = 1.f / s;
        float ent = 0.f;
#pragma unroll
        for (int e = 0; e < NEXP; ++e) { p[e] *= inv; ent -= p[e] * logf(p[e] + 1e-10f); }
        int e1 = 0; float b1 = p[0];
#pragma unroll
        for (int e = 1; e < NEXP; ++e) if (p[e] > b1) { b1 = p[e]; e1 = e; }
        int e2 = (e1 == 0) ? 1 : 0; float b2 = p[e2];
#pragma unroll
        for (int e = 0; e < NEXP; ++e)
            if (e != e1 && e != ((e1 == 0) ? 1 : 0) && p[e] > b2) { b2 = p[e]; e2 = e; }
        topk_idx[2 * t]     = e1;  topk_idx[2 * t + 1] = e2;
        topk_w[2 * t]       = b1;  topk_w[2 * t + 1]   = b2;
        ent_s[wv] = ent;
    }
    __syncthreads();
    if (threadIdx.x == 0)
        ent_partial[blockIdx.x] = ent_s[0] + ent_s[1] + ent_s[2] + ent_s[3];
}

// ---------------------------------------------------------------------------
// Kernel 2: scatter. LDS-binned, fixed per-expert regions.
// ---------------------------------------------------------------------------
__global__ __launch_bounds__(256) void scatter_kernel(
    const int* __restrict__ topk_idx, const float* __restrict__ topk_w,
    int* __restrict__ cursors, int* __restrict__ tok_list,
    float* __restrict__ w_list)
{
    __shared__ int lcnt[NEXP], lbase[NEXP];
    const int tid = threadIdx.x;
    const int t = blockIdx.x * 256 + tid;
    if (tid < NEXP) lcnt[tid] = 0;
    __syncthreads();
    int e0 = topk_idx[2 * t], e1 = topk_idx[2 * t + 1];
    float w0 = topk_w[2 * t], w1 = topk_w[2 * t + 1];
    int p0 = atomicAdd(&lcnt[e0], 1);
    int p1 = atomicAdd(&lcnt[e1], 1);
    __syncthreads();
    if (tid < NEXP) lbase[tid] = atomicAdd(&cursors[tid], lcnt[tid]);
    __syncthreads();
    int d0 = e0 * REGION + lbase[e0] + p0;
    int d1 = e1 * REGION + lbase[e1] + p1;
    tok_list[d0] = t;  w_list[d0] = w0;
    tok_list[d1] = t;  w_list[d1] = w1;
}

// ---------------------------------------------------------------------------
// Kernel 3: finalize — entropy reduce + overuse penalty (counts = cursors).
// ---------------------------------------------------------------------------
__global__ __launch_bounds__(256) void finalize_kernel(
    const int* __restrict__ counts, const float* __restrict__ ent_partial,
    float* __restrict__ loss_out)
{
    __shared__ float red[256];
    float s = 0.f;
    for (int i = threadIdx.x; i < N_TOK / 4; i += 256) s += ent_partial[i];
    red[threadIdx.x] = s;
    __syncthreads();
    for (int st = 128; st > 0; st >>= 1) {
        if (threadIdx.x < st) red[threadIdx.x] += red[threadIdx.x + st];
        __syncthreads();
    }
    if (threadIdx.x == 0) {
        float loss = ENT_W * red[0] / (float)N_TOK;
        for (int e = 0; e < NEXP; ++e) {
            float r = (float)counts[e] / (float)N_TOK - MAX_USAGE;
            if (r > 0.f) loss += r;
        }
        loss_out[0] = loss;
    }
}

// ---------------------------------------------------------------------------
// Kernel 4: grouped GEMM — flatmm-style: A (gathered tokens) via LDS with
// depth-2 counted-vmcnt pipeline (as round 5); B (weights) loaded DIRECTLY
// to registers from fragment-major wb2 (coalesced 1KB wave loads, no LDS).
// LDS halves to 34 KB -> 3 blocks/CU (launch_bounds 256,3).
// Per tile t, per-wave VMEM queue: [A(t+1):4, B(t):8, A(t+2):4];
// vmcnt(4) before MFMA certifies B(t) AND A(t+1); barrier makes it
// block-wide. No vmcnt(0) in steady state.
// ---------------------------------------------------------------------------
__global__ __launch_bounds__(256, 3) void moe_gemm(
    const short* __restrict__ xb, const short* __restrict__ wb2,
    const float* __restrict__ expert_b, const int* __restrict__ tok_list,
    const float* __restrict__ w_list, const int* __restrict__ counts,
    float* __restrict__ out)
{
    const int bid = blockIdx.x;
    const int e   = bid / (TM_MAX * TILES_H);
    const int rem = bid % (TM_MAX * TILES_H);
    const int th  = rem / TM_MAX;      // tm inner: consecutive bids share B panel
    const int tm  = rem % TM_MAX;

    const int cnt = counts[e];
    if (tm * TM >= cnt) return;
    const int valid = cnt - tm * TM;
    const int hbase = th * TH;

    __shared__ __align__(16) short A_s[2][BUFSZ];   // 2 x 16 KB (A only)
    __shared__ int   tok_s[TM];
    __shared__ float wgt_s[TM];

    const int tid = threadIdx.x;
    if (tid < TM) {
        bool v = tid < valid;
        int src = e * REGION + tm * TM + tid;
        tok_s[tid] = v ? tok_list[src] : 0;
        wgt_s[tid] = v ? w_list[src] : 0.f;
    }
    __syncthreads();

    const int lane = tid & 63;
    const int wv = tid >> 6;

    // A staging: wave wv owns 1KB chunks c = wv*4+j. chunk c covers rows
    // 8c..8c+7; lane l -> row c*8+(l>>3), slot (l&7)^(row&7) (involution),
    // LDS dest linear (rule 21 both-sides).
    const char* asrc[4];
    int dst_off[4];
#pragma unroll
    for (int j = 0; j < 4; ++j) {
        int c = wv * 4 + j;
        int r = c * 8 + (lane >> 3);
        int c16 = (lane & 7) ^ (r & 7);
        asrc[j] = (const char*)(xb + (size_t)tok_s[r] * D_IN) + c16 * 16;
        dst_off[j] = c * 512;
    }

    const int rr = lane & 15, kg = lane >> 4;
    const int wr = wv >> 1, wc = wv & 1;

    // A fragment LDS offsets (shorts), swizzled to match staging involution
    int aoff[4][2];
#pragma unroll
    for (int mi = 0; mi < 4; ++mi)
#pragma unroll
        for (int k2 = 0; k2 < 2; ++k2) {
            int row = wr * 64 + mi * 16 + rr;
            int c16 = (k2 * 4 + kg) ^ (row & 7);
            aoff[mi][k2] = row * 64 + c16 * 8;
        }

    // B fragment-major base: chunk = ((e*32+kt)*256 + hgrp)*128 + k2*64 + lane
    // frag(ni,k2) byte offset from base = ni*2048 + k2*1024; kt stride 512 KB.
    unsigned long long b0 =
        (unsigned long long)(uintptr_t)wb2 +
        (((unsigned long long)e * 8192 + (unsigned long long)(th * 8 + wc * 4)) * 128
         + lane) * 16ull;
    unsigned long long b1 = b0 + 4096;

    f32x4 acc[4][4] = {};

    // prologue: stage A-tiles 0 (buf0) and 1 (buf1); certify tile 0.
#pragma unroll
    for (int j = 0; j < 4; ++j) {
        gload16(asrc[j], (short*)A_s[0] + dst_off[j]); asrc[j] += BK * 2;
    }
#pragma unroll
    for (int j = 0; j < 4; ++j) {
        gload16(asrc[j], (short*)A_s[1] + dst_off[j]); asrc[j] += BK * 2;
    }
    asm volatile("s_waitcnt vmcnt(4)" ::: "memory");   // A(0) landed
    __builtin_amdgcn_sched_barrier(0);
    __builtin_amdgcn_s_barrier();

    for (int kt = 0; kt < NKT; ++kt) {
        const short* Ac = A_s[kt & 1];
        short* An = (short*)A_s[kt & 1];   // freed below; receives tile kt+2

        // B fragment loads for THIS tile (opaque asm; issue at tile top).
        bf16x8 bv[4][2];
        LOADB(bv[0][0], b0, 0);
        LOADB(bv[0][1], b0, 1024);
        LOADB(bv[1][0], b0, 2048);
        LOADB(bv[1][1], b0, 3072);
        LOADB(bv[2][0], b1, 0);
        LOADB(bv[2][1], b1, 1024);
        LOADB(bv[3][0], b1, 2048);
        LOADB(bv[3][1], b1, 3072);
        b0 += 524288ull;  b1 += 524288ull;

        // consume current A tile into registers
        bf16x8 af[4][2];
#pragma unroll
        for (int k2 = 0; k2 < 2; ++k2)
#pragma unroll
            for (int mi = 0; mi < 4; ++mi)
                af[mi][k2] = *(const bf16x8*)&Ac[aoff[mi][k2]];
        asm volatile("s_waitcnt lgkmcnt(0)" ::: "memory");
        __builtin_amdgcn_sched_barrier(0);
        __builtin_amdgcn_s_barrier();          // all waves done reading buf[kt&1]

        // stage A tile kt+2 into the freed buffer; certify B(t)+A(t+1).
        if (kt + 2 < NKT) {
#pragma unroll
            for (int j = 0; j < 4; ++j) {
                gload16(asrc[j], An + dst_off[j]); asrc[j] += BK * 2;
            }
            asm volatile("s_waitcnt vmcnt(4)" ::: "memory");
        } else {
            asm volatile("s_waitcnt vmcnt(0)" ::: "memory");
        }
        __builtin_amdgcn_sched_barrier(0);

        __builtin_amdgcn_s_setprio(1);
#pragma unroll
        for (int k2 = 0; k2 < 2; ++k2)
#pragma unroll
            for (int mi = 0; mi < 4; ++mi)
#pragma unroll
                for (int ni = 0; ni < 4; ++ni)
                    acc[mi][ni] = __builtin_amdgcn_mfma_f32_16x16x32_bf16(
                        af[mi][k2], bv[ni][k2], acc[mi][ni], 0, 0, 0);
        __builtin_amdgcn_s_setprio(0);

        __builtin_amdgcn_s_barrier();          // buf[(kt+1)&1] valid for all
    }

    // epilogue: C/D layout col=lane&15, row=(lane>>4)*4+i
    const float* bias = expert_b + (size_t)e * H_OUT + hbase;
#pragma unroll
    for (int mi = 0; mi < 4; ++mi) {
#pragma unroll
        for (int ni = 0; ni < 4; ++ni) {
            int col = wc * 64 + ni * 16 + rr;
            float be = bias[col];
#pragma unroll
            for (int i = 0; i < 4; ++i) {
                int r = wr * 64 + mi * 16 + kg * 4 + i;
                if (r < valid) {
                    float val = wgt_s[r] * (acc[mi][ni][i] + be);
                    atomicAdd(&out[(size_t)tok_s[r] * H_OUT + hbase + col], val);
                }
            }
        }
    }
}

// ---------------------------------------------------------------------------
// Workspace layout (<= 162 MB):
//   0        topk_idx    64 KB
//   64K      topk_w      64 KB
//   128K     cursors     64 B
//   128K+256 ent_partial 8 KB
//   160K     tok_list    256 KB  (8 regions x 8192)
//   416K     w_list      256 KB
//   1M       xb  bf16    32 MB
//   34M      wb2 bf16    128 MB  (fragment-major)
// ---------------------------------------------------------------------------
extern "C" void kernel_launch(void* const* d_in, const int* in_sizes, int n_in,
                              void* d_out, int out_size, void* d_ws, size_t ws_size,
                              hipStream_t stream) {
    const float* x        = (const float*)d_in[0];
    const float* gate_w   = (const float*)d_in[1];
    const float* gate_b   = (const float*)d_in[2];
    const float* expert_w = (const float*)d_in[3];
    const float* expert_b = (const float*)d_in[4];
    float* out = (float*)d_out;
    char* ws = (char*)d_ws;

    int*   topk_idx    = (int*)(ws);
    float* topk_w      = (float*)(ws + (64 << 10));
    int*   cursors     = (int*)(ws + (128 << 10));
    float* ent_partial = (float*)(ws + (128 << 10) + 256);
    int*   tok_list    = (int*)(ws + (160 << 10));
    float* w_list      = (float*)(ws + (416 << 10));
    short* xb          = (short*)(ws + (1ull << 20));
    short* wb2         = (short*)(ws + (34ull << 20));

    hipMemsetAsync(cursors, 0, 64, stream);
    hipMemsetAsync(d_out, 0, (size_t)out_size * sizeof(float), stream);

    gate_kernel<<<N_TOK / 4, 256, 0, stream>>>(x, gate_w, gate_b, topk_idx,
                                               topk_w, ent_partial, xb);
    cvt_wb<<<8192, 256, 0, stream>>>(expert_w, wb2);
    scatter_kernel<<<N_TOK / 256, 256, 0, stream>>>(topk_idx, topk_w, cursors,
                                                    tok_list, w_list);
    finalize_kernel<<<1, 256, 0, stream>>>(cursors, ent_partial,
                                           out + (size_t)N_TOK * H_OUT);
    moe_gemm<<<NEXP * TM_MAX * TILES_H, 256, 0, stream>>>(
        xb, wb2, expert_b, tok_list, w_list, cursors, out);
}

// Round 7
// 832.264 us; speedup vs baseline: 1.2510x; 1.2510x over previous
//
#include <hip/hip_runtime.h>

// Problem constants
constexpr int N_TOK = 8192;      // B*S
constexpr int D_IN  = 2048;
constexpr int H_OUT = 4096;
constexpr int NEXP  = 8;
constexpr float ENT_W = 0.1f;
constexpr float MAX_USAGE = 0.3f;

// GEMM tiling
constexpr int TM = 128;               // token-tile
constexpr int TH = 128;               // H-tile
constexpr int BK = 64;                // K-step (128 bytes bf16 per row)
constexpr int NKT = D_IN / BK;        // 32 K-tiles
constexpr int TILES_H = H_OUT / TH;   // 32
constexpr int TM_MAX  = N_TOK / TM;   // 64 worst-case token tiles per expert
constexpr int REGION  = 8192;         // per-expert list capacity
constexpr int BUFSZ   = TM * BK;      // shorts per A LDS buffer (8192)

typedef __attribute__((ext_vector_type(8))) short bf16x8;
typedef __attribute__((ext_vector_type(4))) float f32x4;

__device__ __forceinline__ short f2bf(float f) {
    unsigned u = __float_as_uint(f);
    u += 0x7FFF + ((u >> 16) & 1);   // RNE
    return (short)(u >> 16);
}

__device__ __forceinline__ void gload16(const void* g, void* l) {
    __builtin_amdgcn_global_load_lds(
        (const __attribute__((address_space(1))) unsigned int*)g,
        (__attribute__((address_space(3))) unsigned int*)l, 16, 0, 0);
}

// Opaque B-fragment load (compiler can't model -> no auto vmcnt drains).
// Data is certified ONLY by our manual counted vmcnt + sched_barrier(0).
#define LOADB(dst, base, OFF) \
    asm volatile("global_load_dwordx4 %0, %1, off offset:" #OFF \
                 : "=v"(dst) : "v"(base) : "memory")

// ---------------------------------------------------------------------------
// cvt_wb: fp32 expert_w -> bf16 in FRAGMENT-MAJOR layout wb2:
//   [e][kt(32)][hgrp(256)][k2(2)][lane(64)][8 elems]
// lane = kg*16+rr maps to (h = hgrp*16+rr, k = kt*64+k2*32+kg*8).
// ---------------------------------------------------------------------------
__global__ __launch_bounds__(256) void cvt_wb(
    const float* __restrict__ in, short* __restrict__ out)
{
    const size_t total = (size_t)NEXP * 32 * 256 * 2 * 64;   // 8.39M chunks
    size_t stride = (size_t)gridDim.x * 256;
    for (size_t d = (size_t)blockIdx.x * 256 + threadIdx.x; d < total; d += stride) {
        int lane = d & 63;
        int k2   = (d >> 6) & 1;
        int hgrp = (d >> 7) & 255;
        int kt   = (d >> 15) & 31;
        int e    = (int)(d >> 20);
        int kg = lane >> 4, rr = lane & 15;
        int h = hgrp * 16 + rr;
        int k = kt * 64 + k2 * 32 + kg * 8;
        const float4* s = (const float4*)(in + ((size_t)e * H_OUT + h) * D_IN + k);
        float4 a = s[0], b = s[1];
        bf16x8 v;
        v[0] = f2bf(a.x); v[1] = f2bf(a.y); v[2] = f2bf(a.z); v[3] = f2bf(a.w);
        v[4] = f2bf(b.x); v[5] = f2bf(b.y); v[6] = f2bf(b.z); v[7] = f2bf(b.w);
        *(bf16x8*)(out + d * 8) = v;
    }
}

// ---------------------------------------------------------------------------
// Kernel 1: gating. One wave per token; fuses x -> bf16 conversion.
// ---------------------------------------------------------------------------
__global__ __launch_bounds__(256) void gate_kernel(
    const float* __restrict__ x, const float* __restrict__ gate_w,
    const float* __restrict__ gate_b, int* __restrict__ topk_idx,
    float* __restrict__ topk_w, float* __restrict__ ent_partial,
    short* __restrict__ xb)
{
    __shared__ float ent_s[4];
    const int wv = threadIdx.x >> 6;
    const int lane = threadIdx.x & 63;
    const int t = blockIdx.x * 4 + wv;

    float acc[NEXP];
#pragma unroll
    for (int e = 0; e < NEXP; ++e) acc[e] = 0.f;

    const float4* xr = (const float4*)(x + (size_t)t * D_IN);
    short* xbr = xb + (size_t)t * D_IN;
#pragma unroll
    for (int i = 0; i < D_IN / 256; ++i) {           // 8 iters
        float4 xv = xr[lane + i * 64];
        short4 s4;
        s4.x = f2bf(xv.x); s4.y = f2bf(xv.y); s4.z = f2bf(xv.z); s4.w = f2bf(xv.w);
        *(short4*)(xbr + i * 256 + lane * 4) = s4;
#pragma unroll
        for (int e = 0; e < NEXP; ++e) {
            float4 gv = ((const float4*)(gate_w + e * D_IN))[lane + i * 64];
            acc[e] += xv.x * gv.x + xv.y * gv.y + xv.z * gv.z + xv.w * gv.w;
        }
    }
#pragma unroll
    for (int e = 0; e < NEXP; ++e)
#pragma unroll
        for (int m = 32; m >= 1; m >>= 1) acc[e] += __shfl_xor(acc[e], m, 64);

    if (lane == 0) {
        float lg[NEXP], p[NEXP];
        float mx = -1e30f;
#pragma unroll
        for (int e = 0; e < NEXP; ++e) { lg[e] = acc[e] + gate_b[e]; mx = fmaxf(mx, lg[e]); }
        float s = 0.f;
#pragma unroll
        for (int e = 0; e < NEXP; ++e) { p[e] = expf(lg[e] - mx); s += p[e]; }
        float inv = 1.f / s;
        float ent = 0.f;
#pragma unroll
        for (int e = 0; e < NEXP; ++e) { p[e] *= inv; ent -= p[e] * logf(p[e] + 1e-10f); }
        int e1 = 0; float b1 = p[0];
#pragma unroll
        for (int e = 1; e < NEXP; ++e) if (p[e] > b1) { b1 = p[e]; e1 = e; }
        int e2 = (e1 == 0) ? 1 : 0; float b2 = p[e2];
#pragma unroll
        for (int e = 0; e < NEXP; ++e)
            if (e != e1 && e != ((e1 == 0) ? 1 : 0) && p[e] > b2) { b2 = p[e]; e2 = e; }
        topk_idx[2 * t]     = e1;  topk_idx[2 * t + 1] = e2;
        topk_w[2 * t]       = b1;  topk_w[2 * t + 1]   = b2;
        ent_s[wv] = ent;
    }
    __syncthreads();
    if (threadIdx.x == 0)
        ent_partial[blockIdx.x] = ent_s[0] + ent_s[1] + ent_s[2] + ent_s[3];
}

// ---------------------------------------------------------------------------
// Kernel 2: scatter. LDS-binned, fixed per-expert regions.
// ---------------------------------------------------------------------------
__global__ __launch_bounds__(256) void scatter_kernel(
    const int* __restrict__ topk_idx, const float* __restrict__ topk_w,
    int* __restrict__ cursors, int* __restrict__ tok_list,
    float* __restrict__ w_list)
{
    __shared__ int lcnt[NEXP], lbase[NEXP];
    const int tid = threadIdx.x;
    const int t = blockIdx.x * 256 + tid;
    if (tid < NEXP) lcnt[tid] = 0;
    __syncthreads();
    int e0 = topk_idx[2 * t], e1 = topk_idx[2 * t + 1];
    float w0 = topk_w[2 * t], w1 = topk_w[2 * t + 1];
    int p0 = atomicAdd(&lcnt[e0], 1);
    int p1 = atomicAdd(&lcnt[e1], 1);
    __syncthreads();
    if (tid < NEXP) lbase[tid] = atomicAdd(&cursors[tid], lcnt[tid]);
    __syncthreads();
    int d0 = e0 * REGION + lbase[e0] + p0;
    int d1 = e1 * REGION + lbase[e1] + p1;
    tok_list[d0] = t;  w_list[d0] = w0;
    tok_list[d1] = t;  w_list[d1] = w1;
}

// ---------------------------------------------------------------------------
// Kernel 3: finalize — entropy reduce + overuse penalty (counts = cursors).
// ---------------------------------------------------------------------------
__global__ __launch_bounds__(256) void finalize_kernel(
    const int* __restrict__ counts, const float* __restrict__ ent_partial,
    float* __restrict__ loss_out)
{
    __shared__ float red[256];
    float s = 0.f;
    for (int i = threadIdx.x; i < N_TOK / 4; i += 256) s += ent_partial[i];
    red[threadIdx.x] = s;
    __syncthreads();
    for (int st = 128; st > 0; st >>= 1) {
        if (threadIdx.x < st) red[threadIdx.x] += red[threadIdx.x + st];
        __syncthreads();
    }
    if (threadIdx.x == 0) {
        float loss = ENT_W * red[0] / (float)N_TOK;
        for (int e = 0; e < NEXP; ++e) {
            float r = (float)counts[e] / (float)N_TOK - MAX_USAGE;
            if (r > 0.f) loss += r;
        }
        loss_out[0] = loss;
    }
}

// ---------------------------------------------------------------------------
// Kernel 4: grouped GEMM, flatmm-style with FULL prefetch depth on both
// operands. A (gathered tokens): LDS depth-2 counted pipeline (r5). B
// (weights): direct-to-register from fragment-major wb2 with a REGISTER
// double buffer (bvA/bvB) — B(t+1) issued at tile-t top, consumed next tile.
// Per-wave VMEM queue at the certify point of tile t:
//   oldest[A(t+1):4, B(t):8 | B(t+1):8, A(t+2):4]newest -> vmcnt(12)
// completes B(t)+A(t+1) with full-tile cover; tail tiles use 8 then 0.
// Block order: th inner (consecutive blocks share the A-tile in L2; B
// re-reads are LLC-resident, wb2 = 128 MB < 256 MB).
// ---------------------------------------------------------------------------
#define GEMM_TILE(t, PB, bvCUR, bvNXT)                                     \
    {                                                                      \
        const short* Ac = A_s[PB];                                         \
        short* An = (short*)A_s[PB];                                       \
        if ((t) + 1 < NKT) {                                               \
            LOADB(bvNXT[0][0], b0, 0);                                     \
            LOADB(bvNXT[0][1], b0, 1024);                                  \
            LOADB(bvNXT[1][0], b0, 2048);                                  \
            LOADB(bvNXT[1][1], b0, 3072);                                  \
            LOADB(bvNXT[2][0], b1, 0);                                     \
            LOADB(bvNXT[2][1], b1, 1024);                                  \
            LOADB(bvNXT[3][0], b1, 2048);                                  \
            LOADB(bvNXT[3][1], b1, 3072);                                  \
            b0 += 524288ull; b1 += 524288ull;                              \
        }                                                                  \
        bf16x8 af[4][2];                                                   \
        _Pragma("unroll")                                                  \
        for (int k2 = 0; k2 < 2; ++k2)                                     \
            _Pragma("unroll")                                              \
            for (int mi = 0; mi < 4; ++mi)                                 \
                af[mi][k2] = *(const bf16x8*)&Ac[aoff[mi][k2]];            \
        asm volatile("s_waitcnt lgkmcnt(0)" ::: "memory");                 \
        __builtin_amdgcn_sched_barrier(0);                                 \
        __builtin_amdgcn_s_barrier();                                      \
        if ((t) + 2 < NKT) {                                               \
            _Pragma("unroll")                                              \
            for (int j = 0; j < 4; ++j) {                                  \
                gload16(asrc[j], An + dst_off[j]); asrc[j] += BK * 2;      \
            }                                                              \
            asm volatile("s_waitcnt vmcnt(12)" ::: "memory");              \
        } else if ((t) + 1 < NKT) {                                        \
            asm volatile("s_waitcnt vmcnt(8)" ::: "memory");               \
        } else {                                                           \
            asm volatile("s_waitcnt vmcnt(0)" ::: "memory");               \
        }                                                                  \
        __builtin_amdgcn_sched_barrier(0);                                 \
        __builtin_amdgcn_s_setprio(1);                                     \
        _Pragma("unroll")                                                  \
        for (int k2 = 0; k2 < 2; ++k2)                                     \
            _Pragma("unroll")                                              \
            for (int mi = 0; mi < 4; ++mi)                                 \
                _Pragma("unroll")                                          \
                for (int ni = 0; ni < 4; ++ni)                             \
                    acc[mi][ni] = __builtin_amdgcn_mfma_f32_16x16x32_bf16( \
                        af[mi][k2], bvCUR[ni][k2], acc[mi][ni], 0, 0, 0);  \
        __builtin_amdgcn_s_setprio(0);                                     \
        __builtin_amdgcn_s_barrier();                                      \
    }

__global__ __launch_bounds__(256) void moe_gemm(
    const short* __restrict__ xb, const short* __restrict__ wb2,
    const float* __restrict__ expert_b, const int* __restrict__ tok_list,
    const float* __restrict__ w_list, const int* __restrict__ counts,
    float* __restrict__ out)
{
    const int bid = blockIdx.x;
    const int e   = bid / (TM_MAX * TILES_H);
    const int rem = bid % (TM_MAX * TILES_H);
    const int tm  = rem / TILES_H;
    const int th  = rem % TILES_H;     // th inner: consecutive bids share A-tile

    const int cnt = counts[e];
    if (tm * TM >= cnt) return;
    const int valid = cnt - tm * TM;
    const int hbase = th * TH;

    __shared__ __align__(16) short A_s[2][BUFSZ];   // 2 x 16 KB (A only)
    __shared__ int   tok_s[TM];
    __shared__ float wgt_s[TM];

    const int tid = threadIdx.x;
    if (tid < TM) {
        bool v = tid < valid;
        int src = e * REGION + tm * TM + tid;
        tok_s[tid] = v ? tok_list[src] : 0;
        wgt_s[tid] = v ? w_list[src] : 0.f;
    }
    __syncthreads();

    const int lane = tid & 63;
    const int wv = tid >> 6;

    // A staging: wave wv owns 1KB chunks c = wv*4+j; lane l -> row c*8+(l>>3),
    // source slot (l&7)^(row&7) (involution), LDS dest linear.
    const char* asrc[4];
    int dst_off[4];
#pragma unroll
    for (int j = 0; j < 4; ++j) {
        int c = wv * 4 + j;
        int r = c * 8 + (lane >> 3);
        int c16 = (lane & 7) ^ (r & 7);
        asrc[j] = (const char*)(xb + (size_t)tok_s[r] * D_IN) + c16 * 16;
        dst_off[j] = c * 512;
    }

    const int rr = lane & 15, kg = lane >> 4;
    const int wr = wv >> 1, wc = wv & 1;

    // A fragment LDS offsets (shorts), swizzled to match staging involution
    int aoff[4][2];
#pragma unroll
    for (int mi = 0; mi < 4; ++mi)
#pragma unroll
        for (int k2 = 0; k2 < 2; ++k2) {
            int row = wr * 64 + mi * 16 + rr;
            int c16 = (k2 * 4 + kg) ^ (row & 7);
            aoff[mi][k2] = row * 64 + c16 * 8;
        }

    // B fragment-major base: chunk = ((e*32+kt)*256 + hgrp)*128 + k2*64 + lane
    unsigned long long b0 =
        (unsigned long long)(uintptr_t)wb2 +
        (((unsigned long long)e * 8192 + (unsigned long long)(th * 8 + wc * 4)) * 128
         + lane) * 16ull;
    unsigned long long b1 = b0 + 4096;

    f32x4 acc[4][4] = {};
    bf16x8 bvA[4][2], bvB[4][2];

    // prologue: stage A(0), A(1); issue B(0) into bvA; certify A(0) only.
#pragma unroll
    for (int j = 0; j < 4; ++j) {
        gload16(asrc[j], (short*)A_s[0] + dst_off[j]); asrc[j] += BK * 2;
    }
#pragma unroll
    for (int j = 0; j < 4; ++j) {
        gload16(asrc[j], (short*)A_s[1] + dst_off[j]); asrc[j] += BK * 2;
    }
    LOADB(bvA[0][0], b0, 0);
    LOADB(bvA[0][1], b0, 1024);
    LOADB(bvA[1][0], b0, 2048);
    LOADB(bvA[1][1], b0, 3072);
    LOADB(bvA[2][0], b1, 0);
    LOADB(bvA[2][1], b1, 1024);
    LOADB(bvA[3][0], b1, 2048);
    LOADB(bvA[3][1], b1, 3072);
    b0 += 524288ull;  b1 += 524288ull;
    asm volatile("s_waitcnt vmcnt(12)" ::: "memory");   // A(0) landed
    __builtin_amdgcn_sched_barrier(0);
    __builtin_amdgcn_s_barrier();

    for (int kt = 0; kt < NKT; kt += 2) {
        GEMM_TILE(kt,     0, bvA, bvB);
        GEMM_TILE(kt + 1, 1, bvB, bvA);
    }

    // epilogue: C/D layout col=lane&15, row=(lane>>4)*4+i
    const float* bias = expert_b + (size_t)e * H_OUT + hbase;
#pragma unroll
    for (int mi = 0; mi < 4; ++mi) {
#pragma unroll
        for (int ni = 0; ni < 4; ++ni) {
            int col = wc * 64 + ni * 16 + rr;
            float be = bias[col];
#pragma unroll
            for (int i = 0; i < 4; ++i) {
                int r = wr * 64 + mi * 16 + kg * 4 + i;
                if (r < valid) {
                    float val = wgt_s[r] * (acc[mi][ni][i] + be);
                    atomicAdd(&out[(size_t)tok_s[r] * H_OUT + hbase + col], val);
                }
            }
        }
    }
}

// ---------------------------------------------------------------------------
// Workspace layout (<= 162 MB):
//   0        topk_idx    64 KB
//   64K      topk_w      64 KB
//   128K     cursors     64 B
//   128K+256 ent_partial 8 KB
//   160K     tok_list    256 KB  (8 regions x 8192)
//   416K     w_list      256 KB
//   1M       xb  bf16    32 MB
//   34M      wb2 bf16    128 MB  (fragment-major)
// ---------------------------------------------------------------------------
extern "C" void kernel_launch(void* const* d_in, const int* in_sizes, int n_in,
                              void* d_out, int out_size, void* d_ws, size_t ws_size,
                              hipStream_t stream) {
    const float* x        = (const float*)d_in[0];
    const float* gate_w   = (const float*)d_in[1];
    const float* gate_b   = (const float*)d_in[2];
    const float* expert_w = (const float*)d_in[3];
    const float* expert_b = (const float*)d_in[4];
    float* out = (float*)d_out;
    char* ws = (char*)d_ws;

    int*   topk_idx    = (int*)(ws);
    float* topk_w      = (float*)(ws + (64 << 10));
    int*   cursors     = (int*)(ws + (128 << 10));
    float* ent_partial = (float*)(ws + (128 << 10) + 256);
    int*   tok_list    = (int*)(ws + (160 << 10));
    float* w_list      = (float*)(ws + (416 << 10));
    short* xb          = (short*)(ws + (1ull << 20));
    short* wb2         = (short*)(ws + (34ull << 20));

    hipMemsetAsync(cursors, 0, 64, stream);
    hipMemsetAsync(d_out, 0, (size_t)out_size * sizeof(float), stream);

    gate_kernel<<<N_TOK / 4, 256, 0, stream>>>(x, gate_w, gate_b, topk_idx,
                                               topk_w, ent_partial, xb);
    cvt_wb<<<8192, 256, 0, stream>>>(expert_w, wb2);
    scatter_kernel<<<N_TOK / 256, 256, 0, stream>>>(topk_idx, topk_w, cursors,
                                                    tok_list, w_list);
    finalize_kernel<<<1, 256, 0, stream>>>(cursors, ent_partial,
                                           out + (size_t)N_TOK * H_OUT);
    moe_gemm<<<NEXP * TM_MAX * TILES_H, 256, 0, stream>>>(
        xb, wb2, expert_b, tok_list, w_list, cursors, out);
}

// Round 8
// 665.002 us; speedup vs baseline: 1.5656x; 1.2515x over previous
//
#include <hip/hip_runtime.h>

// Problem constants
constexpr int N_TOK = 8192;      // B*S
constexpr int D_IN  = 2048;
constexpr int H_OUT = 4096;
constexpr int NEXP  = 8;
constexpr float ENT_W = 0.1f;
constexpr float MAX_USAGE = 0.3f;

// GEMM tiling: 128x128 tile, BK=32 -> 33 KB LDS -> 4 blocks/CU (16 waves/CU)
constexpr int TM = 128;               // token-tile
constexpr int TH = 128;               // H-tile
constexpr int BK = 32;                // K-step (64 bytes bf16 per row)
constexpr int NKT = D_IN / BK;        // 64 K-tiles
constexpr int TILES_H = H_OUT / TH;   // 32
constexpr int TM_MAX  = N_TOK / TM;   // 64 worst-case token tiles per expert
constexpr int REGION  = 8192;         // per-expert list capacity
constexpr int BUFSZ   = TM * BK;      // shorts per LDS buffer (4096 = 8 KB)

typedef __attribute__((ext_vector_type(8))) short bf16x8;
typedef __attribute__((ext_vector_type(4))) float f32x4;

__device__ __forceinline__ short f2bf(float f) {
    unsigned u = __float_as_uint(f);
    u += 0x7FFF + ((u >> 16) & 1);   // RNE
    return (short)(u >> 16);
}

__device__ __forceinline__ void gload16(const void* g, void* l) {
    __builtin_amdgcn_global_load_lds(
        (const __attribute__((address_space(1))) unsigned int*)g,
        (__attribute__((address_space(3))) unsigned int*)l, 16, 0, 0);
}

// ---------------------------------------------------------------------------
// fp32 -> bf16 bulk convert (expert_w, plain row-major; x fused into gate)
// ---------------------------------------------------------------------------
__global__ __launch_bounds__(256) void cvt_kernel(
    const float* __restrict__ in, short* __restrict__ out, int n8)
{
    int stride = gridDim.x * 256;
    for (int i = blockIdx.x * 256 + threadIdx.x; i < n8; i += stride) {
        const float4* p = (const float4*)in + (size_t)i * 2;
        float4 a = p[0], b = p[1];
        bf16x8 v;
        v[0] = f2bf(a.x); v[1] = f2bf(a.y); v[2] = f2bf(a.z); v[3] = f2bf(a.w);
        v[4] = f2bf(b.x); v[5] = f2bf(b.y); v[6] = f2bf(b.z); v[7] = f2bf(b.w);
        *(bf16x8*)(out + (size_t)i * 8) = v;
    }
}

// ---------------------------------------------------------------------------
// Kernel 1: gating. One wave per token; fuses x -> bf16 conversion.
// ---------------------------------------------------------------------------
__global__ __launch_bounds__(256) void gate_kernel(
    const float* __restrict__ x, const float* __restrict__ gate_w,
    const float* __restrict__ gate_b, int* __restrict__ topk_idx,
    float* __restrict__ topk_w, float* __restrict__ ent_partial,
    short* __restrict__ xb)
{
    __shared__ float ent_s[4];
    const int wv = threadIdx.x >> 6;
    const int lane = threadIdx.x & 63;
    const int t = blockIdx.x * 4 + wv;

    float acc[NEXP];
#pragma unroll
    for (int e = 0; e < NEXP; ++e) acc[e] = 0.f;

    const float4* xr = (const float4*)(x + (size_t)t * D_IN);
    short* xbr = xb + (size_t)t * D_IN;
#pragma unroll
    for (int i = 0; i < D_IN / 256; ++i) {           // 8 iters
        float4 xv = xr[lane + i * 64];
        short4 s4;
        s4.x = f2bf(xv.x); s4.y = f2bf(xv.y); s4.z = f2bf(xv.z); s4.w = f2bf(xv.w);
        *(short4*)(xbr + i * 256 + lane * 4) = s4;
#pragma unroll
        for (int e = 0; e < NEXP; ++e) {
            float4 gv = ((const float4*)(gate_w + e * D_IN))[lane + i * 64];
            acc[e] += xv.x * gv.x + xv.y * gv.y + xv.z * gv.z + xv.w * gv.w;
        }
    }
#pragma unroll
    for (int e = 0; e < NEXP; ++e)
#pragma unroll
        for (int m = 32; m >= 1; m >>= 1) acc[e] += __shfl_xor(acc[e], m, 64);

    if (lane == 0) {
        float lg[NEXP], p[NEXP];
        float mx = -1e30f;
#pragma unroll
        for (int e = 0; e < NEXP; ++e) { lg[e] = acc[e] + gate_b[e]; mx = fmaxf(mx, lg[e]); }
        float s = 0.f;
#pragma unroll
        for (int e = 0; e < NEXP; ++e) { p[e] = expf(lg[e] - mx); s += p[e]; }
        float inv = 1.f / s;
        float ent = 0.f;
#pragma unroll
        for (int e = 0; e < NEXP; ++e) { p[e] *= inv; ent -= p[e] * logf(p[e] + 1e-10f); }
        int e1 = 0; float b1 = p[0];
#pragma unroll
        for (int e = 1; e < NEXP; ++e) if (p[e] > b1) { b1 = p[e]; e1 = e; }
        int e2 = (e1 == 0) ? 1 : 0; float b2 = p[e2];
#pragma unroll
        for (int e = 0; e < NEXP; ++e)
            if (e != e1 && e != ((e1 == 0) ? 1 : 0) && p[e] > b2) { b2 = p[e]; e2 = e; }
        topk_idx[2 * t]     = e1;  topk_idx[2 * t + 1] = e2;
        topk_w[2 * t]       = b1;  topk_w[2 * t + 1]   = b2;
        ent_s[wv] = ent;
    }
    __syncthreads();
    if (threadIdx.x == 0)
        ent_partial[blockIdx.x] = ent_s[0] + ent_s[1] + ent_s[2] + ent_s[3];
}

// ---------------------------------------------------------------------------
// Kernel 2: scatter. LDS-binned, fixed per-expert regions.
// ---------------------------------------------------------------------------
__global__ __launch_bounds__(256) void scatter_kernel(
    const int* __restrict__ topk_idx, const float* __restrict__ topk_w,
    int* __restrict__ cursors, int* __restrict__ tok_list,
    float* __restrict__ w_list)
{
    __shared__ int lcnt[NEXP], lbase[NEXP];
    const int tid = threadIdx.x;
    const int t = blockIdx.x * 256 + tid;
    if (tid < NEXP) lcnt[tid] = 0;
    __syncthreads();
    int e0 = topk_idx[2 * t], e1 = topk_idx[2 * t + 1];
    float w0 = topk_w[2 * t], w1 = topk_w[2 * t + 1];
    int p0 = atomicAdd(&lcnt[e0], 1);
    int p1 = atomicAdd(&lcnt[e1], 1);
    __syncthreads();
    if (tid < NEXP) lbase[tid] = atomicAdd(&cursors[tid], lcnt[tid]);
    __syncthreads();
    int d0 = e0 * REGION + lbase[e0] + p0;
    int d1 = e1 * REGION + lbase[e1] + p1;
    tok_list[d0] = t;  w_list[d0] = w0;
    tok_list[d1] = t;  w_list[d1] = w1;
}

// ---------------------------------------------------------------------------
// Kernel 3: finalize — entropy reduce + overuse penalty (counts = cursors).
// ---------------------------------------------------------------------------
__global__ __launch_bounds__(256) void finalize_kernel(
    const int* __restrict__ counts, const float* __restrict__ ent_partial,
    float* __restrict__ loss_out)
{
    __shared__ float red[256];
    float s = 0.f;
    for (int i = threadIdx.x; i < N_TOK / 4; i += 256) s += ent_partial[i];
    red[threadIdx.x] = s;
    __syncthreads();
    for (int st = 128; st > 0; st >>= 1) {
        if (threadIdx.x < st) red[threadIdx.x] += red[threadIdx.x + st];
        __syncthreads();
    }
    if (threadIdx.x == 0) {
        float loss = ENT_W * red[0] / (float)N_TOK;
        for (int e = 0; e < NEXP; ++e) {
            float r = (float)counts[e] / (float)N_TOK - MAX_USAGE;
            if (r > 0.f) loss += r;
        }
        loss_out[0] = loss;
    }
}

// ---------------------------------------------------------------------------
// Kernel 4: grouped GEMM — r5's proven depth-2 counted pipeline at BK=32:
// LDS 33 KB -> 4 blocks/CU; blocks sit on independent barriers and fill
// each other's latency (the m97 12-waves/CU mechanism).
//   tile t: 8 ds_read (4 A + 4 B frags); lgkmcnt(0); s_barrier
//           stage tile t+2 (2A+2B gloads) into freed buf; 16 MFMA;
//           vmcnt(4) certifies tile t+1 (issued a full tile ago); s_barrier
// Swizzle (BK=32, 64B rows): stage source slot (l&3)^((l>>3)&3), LDS dest
// linear; frag read slot kg^((row>>1)&3). 2 lanes/bank-quad = conflict-free.
// ---------------------------------------------------------------------------
__global__ __launch_bounds__(256, 4) void moe_gemm(
    const short* __restrict__ xb, const short* __restrict__ wb,
    const float* __restrict__ expert_b, const int* __restrict__ tok_list,
    const float* __restrict__ w_list, const int* __restrict__ counts,
    float* __restrict__ out)
{
    const int bid = blockIdx.x;
    const int e   = bid / (TM_MAX * TILES_H);
    const int rem = bid % (TM_MAX * TILES_H);
    const int tm  = rem / TILES_H;
    const int th  = rem % TILES_H;     // th inner: consecutive bids share A-tile

    const int cnt = counts[e];
    if (tm * TM >= cnt) return;
    const int valid = cnt - tm * TM;
    const int hbase = th * TH;

    __shared__ __align__(16) short A_s[2][BUFSZ];   // 2 x 8 KB
    __shared__ __align__(16) short B_s[2][BUFSZ];   // 2 x 8 KB
    __shared__ int   tok_s[TM];
    __shared__ float wgt_s[TM];

    const int tid = threadIdx.x;
    if (tid < TM) {
        bool v = tid < valid;
        int src = e * REGION + tm * TM + tid;
        tok_s[tid] = v ? tok_list[src] : 0;
        wgt_s[tid] = v ? w_list[src] : 0.f;
    }
    __syncthreads();

    const int lane = tid & 63;
    const int wv = tid >> 6;

    // staging: 8 x 1KB chunks per operand-tile; wave wv owns chunks wv*2+j.
    // chunk c covers rows c*16..c*16+15; lane l -> row c*16+(l>>2),
    // source slot (l&3)^((l>>3)&3) (involution; (row>>1)&3 == (l>>3)&3).
    const char* asrc[2];
    const char* bsrc[2];
    int dst_off[2];                    // shorts, wave-uniform (+lane*16B by HW)
#pragma unroll
    for (int j = 0; j < 2; ++j) {
        int c = wv * 2 + j;
        int r = c * 16 + (lane >> 2);
        int s2 = (lane & 3) ^ ((lane >> 3) & 3);
        asrc[j] = (const char*)(xb + (size_t)tok_s[r] * D_IN) + s2 * 16;
        bsrc[j] = (const char*)(wb + ((size_t)e * H_OUT + hbase + r) * D_IN) + s2 * 16;
        dst_off[j] = c * 512;
    }

    const int rr = lane & 15, kg = lane >> 4;
    const int wr = wv >> 1, wc = wv & 1;

    // fragment LDS offsets (shorts), swizzled to match staging involution
    int aoff[4], boff[4];
#pragma unroll
    for (int mi = 0; mi < 4; ++mi) {
        int row = wr * 64 + mi * 16 + rr;
        aoff[mi] = row * 32 + (kg ^ ((row >> 1) & 3)) * 8;
        int rowb = wc * 64 + mi * 16 + rr;
        boff[mi] = rowb * 32 + (kg ^ ((rowb >> 1) & 3)) * 8;
    }

    f32x4 acc[4][4] = {};

    // prologue: stage K-tiles 0 (buf0) and 1 (buf1); certify tile 0 only.
#pragma unroll
    for (int j = 0; j < 2; ++j) {
        gload16(asrc[j], (short*)A_s[0] + dst_off[j]); asrc[j] += BK * 2;
        gload16(bsrc[j], (short*)B_s[0] + dst_off[j]); bsrc[j] += BK * 2;
    }
#pragma unroll
    for (int j = 0; j < 2; ++j) {
        gload16(asrc[j], (short*)A_s[1] + dst_off[j]); asrc[j] += BK * 2;
        gload16(bsrc[j], (short*)B_s[1] + dst_off[j]); bsrc[j] += BK * 2;
    }
    asm volatile("s_waitcnt vmcnt(4)" ::: "memory");   // tile 0 landed
    __builtin_amdgcn_sched_barrier(0);
    __builtin_amdgcn_s_barrier();

    for (int kt = 0; kt < NKT; ++kt) {
        const short* Ac = A_s[kt & 1];
        const short* Bc = B_s[kt & 1];
        short* An = (short*)A_s[kt & 1];   // freed below; receives tile kt+2
        short* Bn = (short*)B_s[kt & 1];

        // consume current tile entirely into registers
        bf16x8 af[4], bv[4];
#pragma unroll
        for (int mi = 0; mi < 4; ++mi) af[mi] = *(const bf16x8*)&Ac[aoff[mi]];
#pragma unroll
        for (int ni = 0; ni < 4; ++ni) bv[ni] = *(const bf16x8*)&Bc[boff[ni]];
        asm volatile("s_waitcnt lgkmcnt(0)" ::: "memory");
        __builtin_amdgcn_sched_barrier(0);
        __builtin_amdgcn_s_barrier();          // all waves done reading buf[kt&1]

        // stage tile kt+2 into the freed buffer (loads fly under MFMA)
        if (kt + 2 < NKT) {
#pragma unroll
            for (int j = 0; j < 2; ++j) {
                gload16(asrc[j], An + dst_off[j]); asrc[j] += BK * 2;
                gload16(bsrc[j], Bn + dst_off[j]); bsrc[j] += BK * 2;
            }
        }

        __builtin_amdgcn_s_setprio(1);
#pragma unroll
        for (int mi = 0; mi < 4; ++mi)
#pragma unroll
            for (int ni = 0; ni < 4; ++ni)
                acc[mi][ni] = __builtin_amdgcn_mfma_f32_16x16x32_bf16(
                    af[mi], bv[ni], acc[mi][ni], 0, 0, 0);
        __builtin_amdgcn_s_setprio(0);

        // certify tile kt+1 (issued one full tile ago); never drain deep
        // prefetch in steady state.
        if (kt + 2 < NKT) {
            asm volatile("s_waitcnt vmcnt(4)" ::: "memory");
        } else if (kt + 1 < NKT) {
            asm volatile("s_waitcnt vmcnt(0)" ::: "memory");
        }
        __builtin_amdgcn_sched_barrier(0);
        __builtin_amdgcn_s_barrier();          // buf[(kt+1)&1] valid for all
    }

    // epilogue: C/D layout col=lane&15, row=(lane>>4)*4+i
    const float* bias = expert_b + (size_t)e * H_OUT + hbase;
#pragma unroll
    for (int mi = 0; mi < 4; ++mi) {
#pragma unroll
        for (int ni = 0; ni < 4; ++ni) {
            int col = wc * 64 + ni * 16 + rr;
            float be = bias[col];
#pragma unroll
            for (int i = 0; i < 4; ++i) {
                int r = wr * 64 + mi * 16 + kg * 4 + i;
                if (r < valid) {
                    float val = wgt_s[r] * (acc[mi][ni][i] + be);
                    atomicAdd(&out[(size_t)tok_s[r] * H_OUT + hbase + col], val);
                }
            }
        }
    }
}

// ---------------------------------------------------------------------------
// Workspace layout (<= 162 MB):
//   0        topk_idx    64 KB
//   64K      topk_w      64 KB
//   128K     cursors     64 B
//   128K+256 ent_partial 8 KB
//   160K     tok_list    256 KB  (8 regions x 8192)
//   416K     w_list      256 KB
//   1M       xb  bf16    32 MB
//   34M      wb  bf16    128 MB  (row-major)
// ---------------------------------------------------------------------------
extern "C" void kernel_launch(void* const* d_in, const int* in_sizes, int n_in,
                              void* d_out, int out_size, void* d_ws, size_t ws_size,
                              hipStream_t stream) {
    const float* x        = (const float*)d_in[0];
    const float* gate_w   = (const float*)d_in[1];
    const float* gate_b   = (const float*)d_in[2];
    const float* expert_w = (const float*)d_in[3];
    const float* expert_b = (const float*)d_in[4];
    float* out = (float*)d_out;
    char* ws = (char*)d_ws;

    int*   topk_idx    = (int*)(ws);
    float* topk_w      = (float*)(ws + (64 << 10));
    int*   cursors     = (int*)(ws + (128 << 10));
    float* ent_partial = (float*)(ws + (128 << 10) + 256);
    int*   tok_list    = (int*)(ws + (160 << 10));
    float* w_list      = (float*)(ws + (416 << 10));
    short* xb          = (short*)(ws + (1ull << 20));
    short* wb          = (short*)(ws + (34ull << 20));

    hipMemsetAsync(cursors, 0, 64, stream);
    hipMemsetAsync(d_out, 0, (size_t)out_size * sizeof(float), stream);

    gate_kernel<<<N_TOK / 4, 256, 0, stream>>>(x, gate_w, gate_b, topk_idx,
                                               topk_w, ent_partial, xb);
    cvt_kernel<<<4096, 256, 0, stream>>>(expert_w, wb, (NEXP * H_OUT * D_IN) / 8);
    scatter_kernel<<<N_TOK / 256, 256, 0, stream>>>(topk_idx, topk_w, cursors,
                                                    tok_list, w_list);
    finalize_kernel<<<1, 256, 0, stream>>>(cursors, ent_partial,
                                           out + (size_t)N_TOK * H_OUT);
    moe_gemm<<<NEXP * TM_MAX * TILES_H, 256, 0, stream>>>(
        xb, wb, expert_b, tok_list, w_list, cursors, out);
}